// Round 4
// baseline (173.617 us; speedup 1.0000x reference)
//
#include <hip/hip_runtime.h>
#include <hip/hip_bf16.h>

// Problem constants (fixed-shape problem)
constexpr int B_ = 8, C_ = 21, H_ = 512, W_ = 512;
constexpr int HW = H_ * W_;             // 262144
constexpr long long NPIX = (long long)B_ * HW;  // 2097152
constexpr int GROUPS = (int)(NPIX / 4); // 524288 float4-groups of pixels
constexpr int GROUPS_PER_B = HW / 4;    // 65536  (power of two)
constexpr float INV_N = 1.0f / (float)NPIX;
constexpr int NPART = 32;               // histogram partial rows (spread atomics)
constexpr int NOUT  = 32;               // striped output partials

// ws layout:
//   [0      .. 4096)  part:     NPART x 32 u32 partial histogram counters
//   [4096   .. 4224)  out_part: NOUT f32 striped loss partials
//   [4224   .. 4228)  ticket:   completion counter for last-block reduction
//   [8192   .. ...)   labels4:  GROUPS u32 packed uchar4 labels
// memset zeroes [0, 8192) each call.

// ---------------- Kernel A: ballot histogram + packed labels -------------
__global__ __launch_bounds__(256) void bsl_hist_kernel(
    const float* __restrict__ target,
    unsigned* __restrict__ part,      // [NPART][32] (pre-zeroed)
    unsigned* __restrict__ labels4)   // [GROUPS]
{
    __shared__ unsigned hist[4][C_];
    const int tid  = threadIdx.x;
    const int wave = tid >> 6;

    const int g   = blockIdx.x * 256 + tid;        // one group per thread
    const int b   = g >> 16;                       // g / GROUPS_PER_B
    const int rem = g & (GROUPS_PER_B - 1);
    const float* tb = target + (size_t)b * C_ * HW + (size_t)rem * 4;

    // batch all 21 loads in flight (static-indexed -> VGPRs)
    float4 tv[C_];
    #pragma unroll
    for (int c = 0; c < C_; ++c)
        tv[c] = *(const float4*)(tb + (size_t)c * HW);

    int lx = 0, ly = 0, lz = 0, lw = 0;
    unsigned wc[C_];                  // per-wave channel counts (scalar pipe)
    #pragma unroll
    for (int c = 0; c < C_; ++c) {
        const bool bx = tv[c].x > 0.5f;
        const bool by = tv[c].y > 0.5f;
        const bool bz = tv[c].z > 0.5f;
        const bool bw = tv[c].w > 0.5f;
        if (bx) lx = c;
        if (by) ly = c;
        if (bz) lz = c;
        if (bw) lw = c;
        wc[c] = (unsigned)(__popcll(__ballot(bx)) + __popcll(__ballot(by))
                         + __popcll(__ballot(bz)) + __popcll(__ballot(bw)));
    }
    labels4[g] = (unsigned)lx | ((unsigned)ly << 8) | ((unsigned)lz << 16) | ((unsigned)lw << 24);

    if ((tid & 63) == 0) {
        #pragma unroll
        for (int c = 0; c < C_; ++c) hist[wave][c] = wc[c];
    }
    __syncthreads();
    if (tid < C_) {
        unsigned s = hist[0][tid] + hist[1][tid] + hist[2][tid] + hist[3][tid];
        atomicAdd(&part[(blockIdx.x & (NPART - 1)) * 32 + tid], s);
    }
}

// ---------------- Kernel B: balanced log-softmax at label + reduce -------
// term = p[l] + log f[l] - log( sum_c f[c] * exp(p[c]) )
// No max-subtraction needed: |p| <~ 6 (N(0,1) input), f <= ~2.1e6 -> s < 2e10 (fp32 ok).
__global__ __launch_bounds__(256) void bsl_loss_kernel(
    const float* __restrict__ pred,
    const unsigned* __restrict__ part,
    const unsigned* __restrict__ labels4,
    float* __restrict__ out_part,     // [NOUT] (pre-zeroed)
    unsigned* __restrict__ ticket,    // [1]    (pre-zeroed)
    float* __restrict__ out)          // [1]    written by last block
{
    __shared__ float f_s[C_];
    __shared__ float lf_s[C_];
    __shared__ float wsum[4];
    const int tid  = threadIdx.x;
    const int wave = tid >> 6;

    // part loads first (soonest consumer: the pre-barrier f computation)
    unsigned tot = 0;
    if (tid < C_) {
        #pragma unroll
        for (int p = 0; p < NPART; ++p) tot += part[p * 32 + tid];
    }

    const int g   = blockIdx.x * 256 + tid;
    const int b   = g >> 16;
    const int rem = g & (GROUPS_PER_B - 1);
    const float* pb = pred + (size_t)b * C_ * HW + (size_t)rem * 4;

    const unsigned lab = labels4[g];

    // batch all 21 loads in flight
    float4 vals[C_];
    #pragma unroll
    for (int c = 0; c < C_; ++c)
        vals[c] = *(const float4*)(pb + (size_t)c * HW);

    if (tid < C_) {
        f_s[tid]  = (float)tot;
        lf_s[tid] = __logf((float)tot);
    }
    __syncthreads();

    const int lx = lab & 255, ly = (lab >> 8) & 255, lz = (lab >> 16) & 255, lw = lab >> 24;

    float sx = 0.f, sy = 0.f, sz = 0.f, sw = 0.f;
    float plx = 0.f, ply = 0.f, plz = 0.f, plw = 0.f;
    #pragma unroll
    for (int c = 0; c < C_; ++c) {
        const float f = f_s[c];
        sx = fmaf(f, __expf(vals[c].x), sx);
        sy = fmaf(f, __expf(vals[c].y), sy);
        sz = fmaf(f, __expf(vals[c].z), sz);
        sw = fmaf(f, __expf(vals[c].w), sw);
        if (c == lx) plx = vals[c].x;
        if (c == ly) ply = vals[c].y;
        if (c == lz) plz = vals[c].z;
        if (c == lw) plw = vals[c].w;
    }

    float term = (plx + lf_s[lx] - __logf(sx)) + (ply + lf_s[ly] - __logf(sy))
               + (plz + lf_s[lz] - __logf(sz)) + (plw + lf_s[lw] - __logf(sw));

    #pragma unroll
    for (int off = 32; off > 0; off >>= 1) term += __shfl_down(term, off, 64);
    if ((tid & 63) == 0) wsum[wave] = term;
    __syncthreads();
    if (tid == 0) {
        const float bs = wsum[0] + wsum[1] + wsum[2] + wsum[3];
        atomicAdd(&out_part[blockIdx.x & (NOUT - 1)], bs);
        __threadfence();
        const unsigned t = atomicAdd(ticket, 1u);
        if (t == gridDim.x - 1) {
            __threadfence();
            float totl = 0.f;
            #pragma unroll
            for (int i = 0; i < NOUT; ++i)
                totl += __hip_atomic_load(&out_part[i], __ATOMIC_RELAXED,
                                          __HIP_MEMORY_SCOPE_AGENT);
            *out = -totl * INV_N;
        }
    }
}

// ---------------- Fallback (tiny ws): recompute labels from target -------
__global__ __launch_bounds__(256) void bsl_hist_nolab_kernel(
    const float* __restrict__ target,
    unsigned* __restrict__ part,
    float* __restrict__ out)
{
    __shared__ unsigned hist[4][C_];
    const int tid = threadIdx.x;
    const int wave = tid >> 6;
    if (blockIdx.x == 0 && tid == 0) *out = 0.f;

    const int g   = blockIdx.x * 256 + tid;
    const int b   = g >> 16;
    const int rem = g & (GROUPS_PER_B - 1);
    const float* tb = target + (size_t)b * C_ * HW + (size_t)rem * 4;

    float4 tv[C_];
    #pragma unroll
    for (int c = 0; c < C_; ++c)
        tv[c] = *(const float4*)(tb + (size_t)c * HW);

    unsigned wc[C_];
    #pragma unroll
    for (int c = 0; c < C_; ++c) {
        const bool bx = tv[c].x > 0.5f;
        const bool by = tv[c].y > 0.5f;
        const bool bz = tv[c].z > 0.5f;
        const bool bw = tv[c].w > 0.5f;
        wc[c] = (unsigned)(__popcll(__ballot(bx)) + __popcll(__ballot(by))
                         + __popcll(__ballot(bz)) + __popcll(__ballot(bw)));
    }
    if ((tid & 63) == 0) {
        #pragma unroll
        for (int c = 0; c < C_; ++c) hist[wave][c] = wc[c];
    }
    __syncthreads();
    if (tid < C_) {
        unsigned s = hist[0][tid] + hist[1][tid] + hist[2][tid] + hist[3][tid];
        atomicAdd(&part[(blockIdx.x & (NPART - 1)) * 32 + tid], s);
    }
}

__global__ __launch_bounds__(256) void bsl_loss_fallback_kernel(
    const float* __restrict__ pred,
    const float* __restrict__ target,
    const unsigned* __restrict__ part,
    float* __restrict__ out)
{
    __shared__ float f_s[C_];
    __shared__ float lf_s[C_];
    __shared__ float wsum[4];
    const int tid = threadIdx.x;
    if (tid < C_) {
        unsigned tot = 0;
        #pragma unroll
        for (int p = 0; p < NPART; ++p) tot += part[p * 32 + tid];
        f_s[tid]  = (float)tot;
        lf_s[tid] = __logf((float)tot);
    }
    __syncthreads();

    const int g   = blockIdx.x * 256 + tid;
    const int b   = g >> 16;
    const int rem = g & (GROUPS_PER_B - 1);
    const size_t base = (size_t)b * C_ * HW + (size_t)rem * 4;
    const float* pb = pred + base;
    const float* tb = target + base;

    float sx = 0.f, sy = 0.f, sz = 0.f, sw = 0.f;
    float plx = 0.f, ply = 0.f, plz = 0.f, plw = 0.f;
    float llx = 0.f, lly = 0.f, llz = 0.f, llw = 0.f;
    #pragma unroll
    for (int c = 0; c < C_; ++c) {
        float4 p = *(const float4*)(pb + (size_t)c * HW);
        float4 t = *(const float4*)(tb + (size_t)c * HW);
        const float f = f_s[c];
        const float lf = lf_s[c];
        sx = fmaf(f, __expf(p.x), sx);
        sy = fmaf(f, __expf(p.y), sy);
        sz = fmaf(f, __expf(p.z), sz);
        sw = fmaf(f, __expf(p.w), sw);
        if (t.x > 0.5f) { plx = p.x; llx = lf; }
        if (t.y > 0.5f) { ply = p.y; lly = lf; }
        if (t.z > 0.5f) { plz = p.z; llz = lf; }
        if (t.w > 0.5f) { plw = p.w; llw = lf; }
    }

    float term = (plx + llx - __logf(sx)) + (ply + lly - __logf(sy))
               + (plz + llz - __logf(sz)) + (plw + llw - __logf(sw));

    #pragma unroll
    for (int off = 32; off > 0; off >>= 1) term += __shfl_down(term, off, 64);
    if ((tid & 63) == 0) wsum[tid >> 6] = term;
    __syncthreads();
    if (tid == 0) {
        float bs = wsum[0] + wsum[1] + wsum[2] + wsum[3];
        atomicAdd(out, -bs * INV_N);
    }
}

extern "C" void kernel_launch(void* const* d_in, const int* in_sizes, int n_in,
                              void* d_out, int out_size, void* d_ws, size_t ws_size,
                              hipStream_t stream) {
    const float* pred   = (const float*)d_in[0];
    const float* target = (const float*)d_in[1];
    float* out = (float*)d_out;

    unsigned* part     = (unsigned*)d_ws;
    float*    out_part = (float*)((char*)d_ws + 4096);
    unsigned* ticket   = (unsigned*)((char*)d_ws + 4224);
    unsigned* labels4  = (unsigned*)((char*)d_ws + 8192);
    const size_t need  = 8192 + (size_t)GROUPS * sizeof(unsigned);

    hipMemsetAsync(d_ws, 0, 8192, stream);   // part + out_part + ticket

    const int blocks = GROUPS / 256;  // 2048, exact

    if (ws_size >= need) {
        bsl_hist_kernel<<<blocks, 256, 0, stream>>>(target, part, labels4);
        bsl_loss_kernel<<<blocks, 256, 0, stream>>>(pred, part, labels4,
                                                    out_part, ticket, out);
    } else {
        bsl_hist_nolab_kernel<<<blocks, 256, 0, stream>>>(target, part, out);
        bsl_loss_fallback_kernel<<<blocks, 256, 0, stream>>>(pred, target, part, out);
    }
}

// Round 5
// 84.614 us; speedup vs baseline: 2.0519x; 2.0519x over previous
//
#include <hip/hip_runtime.h>
#include <hip/hip_bf16.h>

// Problem constants (fixed-shape problem)
constexpr int B_ = 8, C_ = 21, H_ = 512, W_ = 512;
constexpr int HW = H_ * W_;             // 262144
constexpr long long NPIX = (long long)B_ * HW;  // 2097152
constexpr int GROUPS = (int)(NPIX / 4); // 524288 float4-groups of pixels
constexpr int GROUPS_PER_B = HW / 4;    // 65536  (power of two)
constexpr float INV_N = 1.0f / (float)NPIX;
constexpr int NPART = 32;               // histogram partial rows (spread atomics)

// ws layout:
//   [0    .. 4096)  part:    NPART x 32 u32 partial histogram counters
//   [4096 .. ...)   labels4: GROUPS u32 packed uchar4 labels
// memset zeroes [0, 4096) each call. Kernel A zeroes *out.

// ---------------- Kernel A: ballot histogram + packed labels -------------
__global__ __launch_bounds__(256) void bsl_hist_kernel(
    const float* __restrict__ target,
    unsigned* __restrict__ part,      // [NPART][32] (pre-zeroed)
    unsigned* __restrict__ labels4,   // [GROUPS]
    float* __restrict__ out)          // zeroed here (stream-ordered before kernel B)
{
    __shared__ unsigned hist[4][C_];
    const int tid  = threadIdx.x;
    const int wave = tid >> 6;
    if (blockIdx.x == 0 && tid == 0) *out = 0.f;

    const int g   = blockIdx.x * 256 + tid;        // one group per thread
    const int b   = g >> 16;                       // g / GROUPS_PER_B
    const int rem = g & (GROUPS_PER_B - 1);
    const float* tb = target + (size_t)b * C_ * HW + (size_t)rem * 4;

    // batch all 21 loads in flight (static-indexed -> VGPRs)
    float4 tv[C_];
    #pragma unroll
    for (int c = 0; c < C_; ++c)
        tv[c] = *(const float4*)(tb + (size_t)c * HW);

    int lx = 0, ly = 0, lz = 0, lw = 0;
    unsigned wc[C_];                  // per-wave channel counts via ballot
    #pragma unroll
    for (int c = 0; c < C_; ++c) {
        const bool bx = tv[c].x > 0.5f;
        const bool by = tv[c].y > 0.5f;
        const bool bz = tv[c].z > 0.5f;
        const bool bw = tv[c].w > 0.5f;
        if (bx) lx = c;
        if (by) ly = c;
        if (bz) lz = c;
        if (bw) lw = c;
        wc[c] = (unsigned)(__popcll(__ballot(bx)) + __popcll(__ballot(by))
                         + __popcll(__ballot(bz)) + __popcll(__ballot(bw)));
    }
    labels4[g] = (unsigned)lx | ((unsigned)ly << 8) | ((unsigned)lz << 16) | ((unsigned)lw << 24);

    if ((tid & 63) == 0) {
        #pragma unroll
        for (int c = 0; c < C_; ++c) hist[wave][c] = wc[c];
    }
    __syncthreads();
    if (tid < C_) {
        unsigned s = hist[0][tid] + hist[1][tid] + hist[2][tid] + hist[3][tid];
        atomicAdd(&part[(blockIdx.x & (NPART - 1)) * 32 + tid], s);
    }
}

// ---------------- Kernel B: balanced log-softmax at label + reduce -------
// term = p[l] + log f[l] - log( sum_c f[c] * exp(p[c]) )
// No max-subtraction needed: |p| <~ 6 (N(0,1) input), f <= ~2.1e6 -> s < 2e10 (fp32 ok).
// EXACT R3 structure (proven fast): f_s/lf_s + barrier BEFORE batched loads,
// plain device-scope atomicAdd at the end (no fence — agent-release fences
// cost ~70ns x 2048 blocks on 8-XCD L2 writeback, measured R4).
__global__ __launch_bounds__(256) void bsl_loss_kernel(
    const float* __restrict__ pred,
    const unsigned* __restrict__ part,
    const unsigned* __restrict__ labels4,
    float* __restrict__ out)
{
    __shared__ float f_s[C_];
    __shared__ float lf_s[C_];
    __shared__ float wsum[4];
    const int tid = threadIdx.x;
    if (tid < C_) {
        unsigned tot = 0;
        #pragma unroll
        for (int p = 0; p < NPART; ++p) tot += part[p * 32 + tid];
        f_s[tid]  = (float)tot;
        lf_s[tid] = __logf((float)tot);
    }
    __syncthreads();

    const int g   = blockIdx.x * 256 + tid;
    const int b   = g >> 16;
    const int rem = g & (GROUPS_PER_B - 1);
    const float* pb = pred + (size_t)b * C_ * HW + (size_t)rem * 4;

    const unsigned lab = labels4[g];
    const int lx = lab & 255, ly = (lab >> 8) & 255, lz = (lab >> 16) & 255, lw = lab >> 24;

    // Load ALL channel values first (static-indexed -> VGPRs)
    float4 vals[C_];
    #pragma unroll
    for (int c = 0; c < C_; ++c)
        vals[c] = *(const float4*)(pb + (size_t)c * HW);

    float sx = 0.f, sy = 0.f, sz = 0.f, sw = 0.f;
    float plx = 0.f, ply = 0.f, plz = 0.f, plw = 0.f;
    #pragma unroll
    for (int c = 0; c < C_; ++c) {
        const float f = f_s[c];
        sx = fmaf(f, __expf(vals[c].x), sx);
        sy = fmaf(f, __expf(vals[c].y), sy);
        sz = fmaf(f, __expf(vals[c].z), sz);
        sw = fmaf(f, __expf(vals[c].w), sw);
        if (c == lx) plx = vals[c].x;
        if (c == ly) ply = vals[c].y;
        if (c == lz) plz = vals[c].z;
        if (c == lw) plw = vals[c].w;
    }

    float term = (plx + lf_s[lx] - __logf(sx)) + (ply + lf_s[ly] - __logf(sy))
               + (plz + lf_s[lz] - __logf(sz)) + (plw + lf_s[lw] - __logf(sw));

    #pragma unroll
    for (int off = 32; off > 0; off >>= 1) term += __shfl_down(term, off, 64);
    if ((tid & 63) == 0) wsum[tid >> 6] = term;
    __syncthreads();
    if (tid == 0) {
        float bs = wsum[0] + wsum[1] + wsum[2] + wsum[3];
        atomicAdd(out, -bs * INV_N);
    }
}

// ---------------- Fallback (tiny ws): recompute labels from target -------
__global__ __launch_bounds__(256) void bsl_hist_nolab_kernel(
    const float* __restrict__ target,
    unsigned* __restrict__ part,
    float* __restrict__ out)
{
    __shared__ unsigned hist[4][C_];
    const int tid = threadIdx.x;
    const int wave = tid >> 6;
    if (blockIdx.x == 0 && tid == 0) *out = 0.f;

    const int g   = blockIdx.x * 256 + tid;
    const int b   = g >> 16;
    const int rem = g & (GROUPS_PER_B - 1);
    const float* tb = target + (size_t)b * C_ * HW + (size_t)rem * 4;

    float4 tv[C_];
    #pragma unroll
    for (int c = 0; c < C_; ++c)
        tv[c] = *(const float4*)(tb + (size_t)c * HW);

    unsigned wc[C_];
    #pragma unroll
    for (int c = 0; c < C_; ++c) {
        const bool bx = tv[c].x > 0.5f;
        const bool by = tv[c].y > 0.5f;
        const bool bz = tv[c].z > 0.5f;
        const bool bw = tv[c].w > 0.5f;
        wc[c] = (unsigned)(__popcll(__ballot(bx)) + __popcll(__ballot(by))
                         + __popcll(__ballot(bz)) + __popcll(__ballot(bw)));
    }
    if ((tid & 63) == 0) {
        #pragma unroll
        for (int c = 0; c < C_; ++c) hist[wave][c] = wc[c];
    }
    __syncthreads();
    if (tid < C_) {
        unsigned s = hist[0][tid] + hist[1][tid] + hist[2][tid] + hist[3][tid];
        atomicAdd(&part[(blockIdx.x & (NPART - 1)) * 32 + tid], s);
    }
}

__global__ __launch_bounds__(256) void bsl_loss_fallback_kernel(
    const float* __restrict__ pred,
    const float* __restrict__ target,
    const unsigned* __restrict__ part,
    float* __restrict__ out)
{
    __shared__ float f_s[C_];
    __shared__ float lf_s[C_];
    __shared__ float wsum[4];
    const int tid = threadIdx.x;
    if (tid < C_) {
        unsigned tot = 0;
        #pragma unroll
        for (int p = 0; p < NPART; ++p) tot += part[p * 32 + tid];
        f_s[tid]  = (float)tot;
        lf_s[tid] = __logf((float)tot);
    }
    __syncthreads();

    const int g   = blockIdx.x * 256 + tid;
    const int b   = g >> 16;
    const int rem = g & (GROUPS_PER_B - 1);
    const size_t base = (size_t)b * C_ * HW + (size_t)rem * 4;
    const float* pb = pred + base;
    const float* tb = target + base;

    float sx = 0.f, sy = 0.f, sz = 0.f, sw = 0.f;
    float plx = 0.f, ply = 0.f, plz = 0.f, plw = 0.f;
    float llx = 0.f, lly = 0.f, llz = 0.f, llw = 0.f;
    #pragma unroll
    for (int c = 0; c < C_; ++c) {
        float4 p = *(const float4*)(pb + (size_t)c * HW);
        float4 t = *(const float4*)(tb + (size_t)c * HW);
        const float f = f_s[c];
        const float lf = lf_s[c];
        sx = fmaf(f, __expf(p.x), sx);
        sy = fmaf(f, __expf(p.y), sy);
        sz = fmaf(f, __expf(p.z), sz);
        sw = fmaf(f, __expf(p.w), sw);
        if (t.x > 0.5f) { plx = p.x; llx = lf; }
        if (t.y > 0.5f) { ply = p.y; lly = lf; }
        if (t.z > 0.5f) { plz = p.z; llz = lf; }
        if (t.w > 0.5f) { plw = p.w; llw = lf; }
    }

    float term = (plx + llx - __logf(sx)) + (ply + lly - __logf(sy))
               + (plz + llz - __logf(sz)) + (plw + llw - __logf(sw));

    #pragma unroll
    for (int off = 32; off > 0; off >>= 1) term += __shfl_down(term, off, 64);
    if ((tid & 63) == 0) wsum[tid >> 6] = term;
    __syncthreads();
    if (tid == 0) {
        float bs = wsum[0] + wsum[1] + wsum[2] + wsum[3];
        atomicAdd(out, -bs * INV_N);
    }
}

extern "C" void kernel_launch(void* const* d_in, const int* in_sizes, int n_in,
                              void* d_out, int out_size, void* d_ws, size_t ws_size,
                              hipStream_t stream) {
    const float* pred   = (const float*)d_in[0];
    const float* target = (const float*)d_in[1];
    float* out = (float*)d_out;

    unsigned* part    = (unsigned*)d_ws;
    unsigned* labels4 = (unsigned*)((char*)d_ws + 4096);
    const size_t need = 4096 + (size_t)GROUPS * sizeof(unsigned);

    hipMemsetAsync(d_ws, 0, 4096, stream);   // zero partial counters

    const int blocks = GROUPS / 256;  // 2048, exact

    if (ws_size >= need) {
        bsl_hist_kernel<<<blocks, 256, 0, stream>>>(target, part, labels4, out);
        bsl_loss_kernel<<<blocks, 256, 0, stream>>>(pred, part, labels4, out);
    } else {
        bsl_hist_nolab_kernel<<<blocks, 256, 0, stream>>>(target, part, out);
        bsl_loss_fallback_kernel<<<blocks, 256, 0, stream>>>(pred, target, part, out);
    }
}

// Round 6
// 79.936 us; speedup vs baseline: 2.1720x; 1.0585x over previous
//
#include <hip/hip_runtime.h>
#include <hip/hip_bf16.h>

// Problem constants (fixed-shape problem)
constexpr int B_ = 8, C_ = 21, H_ = 512, W_ = 512;
constexpr int HW = H_ * W_;             // 262144
constexpr long long NPIX = (long long)B_ * HW;  // 2097152
constexpr int GROUPS = (int)(NPIX / 4); // 524288 float4-groups of pixels
constexpr int GROUPS_PER_B = HW / 4;    // 65536  (power of two)
constexpr float INV_N = 1.0f / (float)NPIX;
constexpr int NPART = 32;               // histogram partial rows (spread atomics)

// ws layout:
//   [0    .. 4096)  part:    NPART x 32 u32 partial histogram counters
//   [4096 .. ...)   labels4: GROUPS u32 packed uchar4 labels
// memset zeroes [0, 4096) each call. Kernel A zeroes *out.

// ---------------- Kernel A: histogram + packed labels (R3-proven) --------
// Max-occupancy streaming: loads interleaved (compiler's choice), LDS-atomic
// per-wave histogram. (R5 showed batching+ballot here costs ~5us.)
__global__ __launch_bounds__(256) void bsl_hist_kernel(
    const float* __restrict__ target,
    unsigned* __restrict__ part,      // [NPART][32] (pre-zeroed)
    unsigned* __restrict__ labels4,   // [GROUPS]
    float* __restrict__ out)          // zeroed here (stream-ordered before kernel B)
{
    __shared__ unsigned hist[4][C_];
    const int tid = threadIdx.x;
    const int wave = tid >> 6;
    if (tid < 4 * C_) ((unsigned*)hist)[tid] = 0u;
    if (blockIdx.x == 0 && tid == 0) *out = 0.f;
    __syncthreads();

    const int g   = blockIdx.x * 256 + tid;        // one group per thread
    const int b   = g >> 16;                       // g / GROUPS_PER_B
    const int rem = g & (GROUPS_PER_B - 1);
    const float* tb = target + (size_t)b * C_ * HW + (size_t)rem * 4;

    int lx = 0, ly = 0, lz = 0, lw = 0;
    #pragma unroll
    for (int c = 0; c < C_; ++c) {
        float4 t = *(const float4*)(tb + (size_t)c * HW);
        if (t.x > 0.5f) lx = c;
        if (t.y > 0.5f) ly = c;
        if (t.z > 0.5f) lz = c;
        if (t.w > 0.5f) lw = c;
    }
    atomicAdd(&hist[wave][lx], 1u);
    atomicAdd(&hist[wave][ly], 1u);
    atomicAdd(&hist[wave][lz], 1u);
    atomicAdd(&hist[wave][lw], 1u);
    labels4[g] = (unsigned)lx | ((unsigned)ly << 8) | ((unsigned)lz << 16) | ((unsigned)lw << 24);

    __syncthreads();
    if (tid < C_) {
        unsigned s = hist[0][tid] + hist[1][tid] + hist[2][tid] + hist[3][tid];
        atomicAdd(&part[(blockIdx.x & (NPART - 1)) * 32 + tid], s);
    }
}

// ---------------- Kernel B: balanced log-softmax at label + reduce -------
// term = p[l] + log f[l] - log( sum_c f[c] * exp(p[c]) )
// No max-subtraction needed: |p| <~ 6 (N(0,1) input), f <= ~2.1e6 -> s < 2e10 (fp32 ok).
// Load order: part (small, L2) first so f_s waits only vmcnt(22); then the
// 21 big vals loads PINNED as a batch (asm barrier stops the compiler from
// sinking them into the fma loop — R4 showed VGPR=60 i.e. sunk loads).
__global__ __launch_bounds__(256, 4) void bsl_loss_kernel(
    const float* __restrict__ pred,
    const unsigned* __restrict__ part,
    const unsigned* __restrict__ labels4,
    float* __restrict__ out)
{
    __shared__ float f_s[C_];
    __shared__ float lf_s[C_];
    __shared__ float wsum[4];
    const int tid  = threadIdx.x;
    const int wave = tid >> 6;

    // small loads first
    unsigned tot = 0;
    if (tid < C_) {
        #pragma unroll
        for (int p = 0; p < NPART; ++p) tot += part[p * 32 + tid];
    }

    const int g   = blockIdx.x * 256 + tid;
    const int b   = g >> 16;
    const int rem = g & (GROUPS_PER_B - 1);
    const float* pb = pred + (size_t)b * C_ * HW + (size_t)rem * 4;

    const unsigned lab = labels4[g];

    // batched big loads — keep all 21 in flight
    float4 vals[C_];
    #pragma unroll
    for (int c = 0; c < C_; ++c)
        vals[c] = *(const float4*)(pb + (size_t)c * HW);
    asm volatile("" ::: "memory");   // pin: no sinking of loads into compute

    if (tid < C_) {
        f_s[tid]  = (float)tot;
        lf_s[tid] = __logf((float)tot);
    }
    __syncthreads();

    const int lx = lab & 255, ly = (lab >> 8) & 255, lz = (lab >> 16) & 255, lw = lab >> 24;

    float sx = 0.f, sy = 0.f, sz = 0.f, sw = 0.f;
    float plx = 0.f, ply = 0.f, plz = 0.f, plw = 0.f;
    #pragma unroll
    for (int c = 0; c < C_; ++c) {
        const float f = f_s[c];
        sx = fmaf(f, __expf(vals[c].x), sx);
        sy = fmaf(f, __expf(vals[c].y), sy);
        sz = fmaf(f, __expf(vals[c].z), sz);
        sw = fmaf(f, __expf(vals[c].w), sw);
        if (c == lx) plx = vals[c].x;
        if (c == ly) ply = vals[c].y;
        if (c == lz) plz = vals[c].z;
        if (c == lw) plw = vals[c].w;
    }

    float term = (plx + lf_s[lx] - __logf(sx)) + (ply + lf_s[ly] - __logf(sy))
               + (plz + lf_s[lz] - __logf(sz)) + (plw + lf_s[lw] - __logf(sw));

    #pragma unroll
    for (int off = 32; off > 0; off >>= 1) term += __shfl_down(term, off, 64);
    if ((tid & 63) == 0) wsum[wave] = term;
    __syncthreads();
    if (tid == 0) {
        float bs = wsum[0] + wsum[1] + wsum[2] + wsum[3];
        atomicAdd(out, -bs * INV_N);
    }
}

// ---------------- Fallback (tiny ws): recompute labels from target -------
__global__ __launch_bounds__(256) void bsl_hist_nolab_kernel(
    const float* __restrict__ target,
    unsigned* __restrict__ part,
    float* __restrict__ out)
{
    __shared__ unsigned hist[4][C_];
    const int tid = threadIdx.x;
    const int wave = tid >> 6;
    if (tid < 4 * C_) ((unsigned*)hist)[tid] = 0u;
    if (blockIdx.x == 0 && tid == 0) *out = 0.f;
    __syncthreads();

    const int g   = blockIdx.x * 256 + tid;
    const int b   = g >> 16;
    const int rem = g & (GROUPS_PER_B - 1);
    const float* tb = target + (size_t)b * C_ * HW + (size_t)rem * 4;

    int lx = 0, ly = 0, lz = 0, lw = 0;
    #pragma unroll
    for (int c = 0; c < C_; ++c) {
        float4 t = *(const float4*)(tb + (size_t)c * HW);
        if (t.x > 0.5f) lx = c;
        if (t.y > 0.5f) ly = c;
        if (t.z > 0.5f) lz = c;
        if (t.w > 0.5f) lw = c;
    }
    atomicAdd(&hist[wave][lx], 1u);
    atomicAdd(&hist[wave][ly], 1u);
    atomicAdd(&hist[wave][lz], 1u);
    atomicAdd(&hist[wave][lw], 1u);

    __syncthreads();
    if (tid < C_) {
        unsigned s = hist[0][tid] + hist[1][tid] + hist[2][tid] + hist[3][tid];
        atomicAdd(&part[(blockIdx.x & (NPART - 1)) * 32 + tid], s);
    }
}

__global__ __launch_bounds__(256) void bsl_loss_fallback_kernel(
    const float* __restrict__ pred,
    const float* __restrict__ target,
    const unsigned* __restrict__ part,
    float* __restrict__ out)
{
    __shared__ float f_s[C_];
    __shared__ float lf_s[C_];
    __shared__ float wsum[4];
    const int tid = threadIdx.x;
    if (tid < C_) {
        unsigned tot = 0;
        #pragma unroll
        for (int p = 0; p < NPART; ++p) tot += part[p * 32 + tid];
        f_s[tid]  = (float)tot;
        lf_s[tid] = __logf((float)tot);
    }
    __syncthreads();

    const int g   = blockIdx.x * 256 + tid;
    const int b   = g >> 16;
    const int rem = g & (GROUPS_PER_B - 1);
    const size_t base = (size_t)b * C_ * HW + (size_t)rem * 4;
    const float* pb = pred + base;
    const float* tb = target + base;

    float sx = 0.f, sy = 0.f, sz = 0.f, sw = 0.f;
    float plx = 0.f, ply = 0.f, plz = 0.f, plw = 0.f;
    float llx = 0.f, lly = 0.f, llz = 0.f, llw = 0.f;
    #pragma unroll
    for (int c = 0; c < C_; ++c) {
        float4 p = *(const float4*)(pb + (size_t)c * HW);
        float4 t = *(const float4*)(tb + (size_t)c * HW);
        const float f = f_s[c];
        const float lf = lf_s[c];
        sx = fmaf(f, __expf(p.x), sx);
        sy = fmaf(f, __expf(p.y), sy);
        sz = fmaf(f, __expf(p.z), sz);
        sw = fmaf(f, __expf(p.w), sw);
        if (t.x > 0.5f) { plx = p.x; llx = lf; }
        if (t.y > 0.5f) { ply = p.y; lly = lf; }
        if (t.z > 0.5f) { plz = p.z; llz = lf; }
        if (t.w > 0.5f) { plw = p.w; llw = lf; }
    }

    float term = (plx + llx - __logf(sx)) + (ply + lly - __logf(sy))
               + (plz + llz - __logf(sz)) + (plw + llw - __logf(sw));

    #pragma unroll
    for (int off = 32; off > 0; off >>= 1) term += __shfl_down(term, off, 64);
    if ((tid & 63) == 0) wsum[tid >> 6] = term;
    __syncthreads();
    if (tid == 0) {
        float bs = wsum[0] + wsum[1] + wsum[2] + wsum[3];
        atomicAdd(out, -bs * INV_N);
    }
}

extern "C" void kernel_launch(void* const* d_in, const int* in_sizes, int n_in,
                              void* d_out, int out_size, void* d_ws, size_t ws_size,
                              hipStream_t stream) {
    const float* pred   = (const float*)d_in[0];
    const float* target = (const float*)d_in[1];
    float* out = (float*)d_out;

    unsigned* part    = (unsigned*)d_ws;
    unsigned* labels4 = (unsigned*)((char*)d_ws + 4096);
    const size_t need = 4096 + (size_t)GROUPS * sizeof(unsigned);

    hipMemsetAsync(d_ws, 0, 4096, stream);   // zero partial counters

    const int blocks = GROUPS / 256;  // 2048, exact

    if (ws_size >= need) {
        bsl_hist_kernel<<<blocks, 256, 0, stream>>>(target, part, labels4, out);
        bsl_loss_kernel<<<blocks, 256, 0, stream>>>(pred, part, labels4, out);
    } else {
        bsl_hist_nolab_kernel<<<blocks, 256, 0, stream>>>(target, part, out);
        bsl_loss_fallback_kernel<<<blocks, 256, 0, stream>>>(pred, target, part, out);
    }
}